// Round 1
// baseline (232.461 us; speedup 1.0000x reference)
//
#include <hip/hip_runtime.h>
#include <math.h>

#define NB 4
#define PP 256
#define CC 151
#define RR 51
#define CM 160                 // padded C (5 tiles of 32)
#define KS 64                  // split-K: 4 i's per block
#define NROW (NB*PP)           // 1024
#define RELTOT (NB*PP*PP*RR)   // 13,369,344 floats
#define MLB 10240              // halves per l in m-layout: 8 oct * 160 c * 8 j

typedef _Float16 half8 __attribute__((ext_vector_type(8)));
typedef float floatx16 __attribute__((ext_vector_type(16)));
typedef float float4v __attribute__((ext_vector_type(4)));

// ws layout (bytes): m1g, m2g, part
#define OFF_M1 ((size_t)0)
#define OFF_M2 (OFF_M1 + (size_t)CC*MLB*2)     // +3,092,480
#define OFF_PT (OFF_M2 + (size_t)CC*MLB*2)     // part: 64*1024*160*4 = 41.9 MB

// ---------------------------------------------------------------------------
// K1: streaming-friendly M layout (unchanged).
// m1g[l][oct][c][j] = w_r * M[l][c][oct*8+j]   (r = oct*8+j)
// m2g[l][oct][c][j] = w_r * M[c][l][oct*8+j]
// ---------------------------------------------------------------------------
__global__ __launch_bounds__(256) void prep_kernel(const float* __restrict__ M,
                                                   _Float16* __restrict__ m1,
                                                   _Float16* __restrict__ m2,
                                                   float* __restrict__ out) {
    const int l = blockIdx.x;      // 0..150
    const int mat = blockIdx.y;    // 0,1
    if (l == 0 && mat == 0 && threadIdx.x == 0) *out = 0.f;
    _Float16* dst = (mat ? m2 : m1) + (size_t)l * MLB;
    for (int e = threadIdx.x; e < MLB; e += 256) {
        int oct = e / 1280;
        int rem = e - oct * 1280;
        int c = rem >> 3, j = rem & 7;
        int r = oct * 8 + j;
        float v = 0.f;
        if (r < RR && c < CC) {
            size_t src = ((size_t)(mat ? c * CC + l : l * CC + c)) * RR + r;
            v = (r == 0 ? 0.5f : 0.25f) * M[src];
        }
        dst[e] = (_Float16)v;
    }
}

// ---------------------------------------------------------------------------
// K2 (fused transpose+GEMM, 32x32x16 MFMA) — counted-vmcnt pipeline (T3+T4):
//   - ALL per-step traffic via global_load_lds: A tile (128 rows x 16 f32,
//     8 x 4B chunks/thread; rel rows are only 4B-aligned) + B slab (5 KB,
//     16B + 4B chunk/thread) => uniform 10 vmem ops/thread/step.
//   - Ring of 4 LDS buffers, prefetch distance 2. Raw s_barrier preceded by
//     s_waitcnt vmcnt(20): retires exactly group h, keeps h+1,h+2 in flight
//     (no vmcnt(0) drain => HBM latency hidden, unlike __syncthreads).
//   - A quads XOR-swizzled by row bits <1,2> (source-side; LDS dest stays
//     lane-linear) to break the 16-way b128 bank conflict of [128][16]f32.
// Grid 512 = 4 img x 2 rowblk x 64 ks.
// ---------------------------------------------------------------------------
__global__ __launch_bounds__(256) void gemm_kernel(const float* __restrict__ rel,
                                                   const _Float16* __restrict__ m1,
                                                   const _Float16* __restrict__ m2,
                                                   const int* __restrict__ labels,
                                                   float* __restrict__ part) {
    __shared__ float    ldsA[4][2048];     // 4 x 8 KB
    __shared__ _Float16 ldsB[4][2560];     // 4 x 5 KB   (total 53,248 B)
    const int tid  = threadIdx.x;
    const int ks   = blockIdx.x & 63;
    const int rbk  = (blockIdx.x >> 6) & 1;
    const int n    = blockIdx.x >> 7;
    const int wave = tid >> 6, lane = tid & 63;
    const int m32  = lane & 31, kh = lane >> 5;
    const int i0   = ks * 4;
    const int row_loc = wave * 32 + m32;          // 0..127 (this lane's A row)
    const int rowimg  = rbk * 128 + row_loc;      // in-image q

    const int l0 = labels[n * PP + i0 + 0];
    const int l1 = labels[n * PP + i0 + 1];
    const int l2 = labels[n * PP + i0 + 2];
    const int l3 = labels[n * PP + i0 + 3];

    // A-read phys quads: stage stored logical quad (q ^ s) at phys q
    const int s_swz = (row_loc >> 1) & 3;
    const int pA    = (2 * kh) ^ s_swz;
    const int aoffL = row_loc * 16 + pA * 4;          // logical floats kh*8..+3
    const int aoffH = row_loc * 16 + (pA ^ 1) * 4;    // logical floats kh*8+4..+7

    floatx16 acc[5];
    #pragma unroll
    for (int ct = 0; ct < 5; ++ct)
        #pragma unroll
        for (int r2 = 0; r2 < 16; ++r2) acc[ct][r2] = 0.f;

    // step h = (i_loc<<3) | (mat<<2) | t ; t = k16-step within the 64 r-slots
    auto issueStep = [&](int h, int buf) {
        const int il = h >> 3, mh = (h >> 2) & 1, t = h & 3;
        const int i = i0 + il;
        const int lab = (il & 2) ? ((il & 1) ? l3 : l2) : ((il & 1) ? l1 : l0);
        // ---- B: 2560 halves = 256x16B + 256x4B, lane-linear dest
        const _Float16* mb = (mh ? m2 : m1) + (size_t)lab * MLB + t * 2560;
        __builtin_amdgcn_global_load_lds(
            (const __attribute__((address_space(1))) unsigned int*)(mb + tid * 8),
            (__attribute__((address_space(3))) unsigned int*)(&ldsB[buf][tid * 8]),
            16, 0, 0);
        __builtin_amdgcn_global_load_lds(
            (const __attribute__((address_space(1))) unsigned int*)(mb + 2048 + tid * 2),
            (__attribute__((address_space(3))) unsigned int*)(&ldsB[buf][2048 + tid * 2]),
            4, 0, 0);
        // ---- A: 2048 f32 = 128 rows x 16, 8 x 4B chunks/thread, quad-swizzled src
        #pragma unroll
        for (int jj = 0; jj < 8; ++jj) {
            const int tau = jj * 256 + tid;          // 0..2047
            const int row = tau >> 4;
            const int q   = (tau >> 2) & 3;
            const int e   = tau & 3;
            const int ql  = q ^ ((row >> 1) & 3);    // logical quad stored here
            const int rg  = rbk * 128 + row;
            int f = (mh ? ((n * PP + rg) * PP + i)
                        : ((n * PP + i) * PP + rg)) * RR + t * 16 + ql * 4 + e;
            f = min(f, RELTOT - 1);   // only reachable on the i==q==255 diag (zeroed)
            __builtin_amdgcn_global_load_lds(
                (const __attribute__((address_space(1))) unsigned int*)(rel + f),
                (__attribute__((address_space(3))) unsigned int*)(&ldsA[buf][tau]),
                4, 0, 0);
        }
    };

    auto computeStep = [&](int h, int buf) {
        const int il = h >> 3;
        const bool dz = (i0 + il) == rowimg;         // diagonal i == q
        const float4v alo = *(const float4v*)(&ldsA[buf][aoffL]);
        const float4v ahi = *(const float4v*)(&ldsA[buf][aoffH]);
        half8 a;
        #pragma unroll
        for (int j = 0; j < 4; ++j) {
            a[j]     = (_Float16)(dz ? 0.f : alo[j]);
            a[j + 4] = (_Float16)(dz ? 0.f : ahi[j]);
        }
        // B-frag: n = m32 (+ct*32), k = kh*8+j -> chunk (kh*160 + ct*32 + m32)
        const _Float16* bb = &ldsB[buf][(kh * 160 + m32) * 8];
        #pragma unroll
        for (int ct = 0; ct < 5; ++ct) {
            half8 b = *(const half8*)(bb + ct * 256);
            acc[ct] = __builtin_amdgcn_mfma_f32_32x32x16_f16(a, b, acc[ct], 0, 0, 0);
        }
    };

    // prologue: groups 0,1 in flight (20 ops/thread)
    issueStep(0, 0);
    issueStep(1, 1);

    for (int h = 0; h < 32; ++h) {
        if (h < 30) issueStep(h + 2, (h + 2) & 3);   // ring WAR-safe: >=2 barriers old
        // retire exactly group h; keep h+1 (,h+2) in flight (10 ops each)
        if (h < 30)       asm volatile("s_waitcnt vmcnt(20)" ::: "memory");
        else if (h == 30) asm volatile("s_waitcnt vmcnt(10)" ::: "memory");
        else              asm volatile("s_waitcnt vmcnt(0)"  ::: "memory");
        __builtin_amdgcn_s_barrier();
        asm volatile("" ::: "memory");               // no ds_read hoist above barrier
        computeStep(h, h & 3);
    }

    // C/D 32x32 layout (m74/m101): col = m32, row = (reg&3) + 8*(reg>>2) + 4*kh
    float* pb = part + ((size_t)ks * NROW + n * PP + rbk * 128 + wave * 32) * CM;
    #pragma unroll
    for (int ct = 0; ct < 5; ++ct)
        #pragma unroll
        for (int reg = 0; reg < 16; ++reg) {
            int row = (reg & 3) + 8 * (reg >> 2) + 4 * kh;
            pb[(size_t)row * CM + ct * 32 + m32] = acc[ct][reg];
        }
}

// ---------------------------------------------------------------------------
// K3: theta[row][c] = sum_ks part; loss = lse(theta) - theta[lab]; mean.
// ---------------------------------------------------------------------------
__global__ __launch_bounds__(256) void reduce_loss_kernel(const float* __restrict__ part,
                                                          const int* __restrict__ labels,
                                                          float* __restrict__ out) {
    __shared__ float th[CM];
    const int row = blockIdx.x;
    const int t = threadIdx.x;
    if (t < CM) {
        float s = 0.f;
        #pragma unroll
        for (int ks = 0; ks < KS; ++ks)
            s += part[((size_t)ks * NROW + row) * CM + t];
        th[t] = s;
    }
    __syncthreads();
    if (t < 64) {
        float v0 = (t < CC)       ? th[t]       : -INFINITY;
        float v1 = (t + 64 < CC)  ? th[t + 64]  : -INFINITY;
        float v2 = (t + 128 < CC) ? th[t + 128] : -INFINITY;
        float m = fmaxf(v0, fmaxf(v1, v2));
        #pragma unroll
        for (int o = 32; o > 0; o >>= 1) m = fmaxf(m, __shfl_xor(m, o, 64));
        float s = 0.f;
        if (t < CC)       s += expf(v0 - m);
        if (t + 64 < CC)  s += expf(v1 - m);
        if (t + 128 < CC) s += expf(v2 - m);
        #pragma unroll
        for (int o = 32; o > 0; o >>= 1) s += __shfl_xor(s, o, 64);
        if (t == 0) {
            atomicAdd(out, (m + logf(s) - th[labels[row]]) * (1.0f / NROW));
        }
    }
}

// ---------------------------------------------------------------------------
extern "C" void kernel_launch(void* const* d_in, const int* in_sizes, int n_in,
                              void* d_out, int out_size, void* d_ws, size_t ws_size,
                              hipStream_t stream) {
    // inputs: 0=roi_scores (unused), 1=rel_scores, 2=relationship_mat,
    //         3=roi_labels, 4=num_images (fixed B=4)
    const float* rel    = (const float*)d_in[1];
    const float* relmat = (const float*)d_in[2];
    const int*   labels = (const int*)d_in[3];
    float* out = (float*)d_out;
    char* ws = (char*)d_ws;

    _Float16* m1 = (_Float16*)(ws + OFF_M1);
    _Float16* m2 = (_Float16*)(ws + OFF_M2);
    float*  part = (float*)(ws + OFF_PT);

    prep_kernel<<<dim3(CC, 2), 256, 0, stream>>>(relmat, m1, m2, out);
    gemm_kernel<<<NB * 2 * KS, 256, 0, stream>>>(rel, m1, m2, labels, part);
    reduce_loss_kernel<<<NROW, 256, 0, stream>>>(part, labels, out);
}

// Round 2
// 173.087 us; speedup vs baseline: 1.3430x; 1.3430x over previous
//
#include <hip/hip_runtime.h>
#include <math.h>

#define NB 4
#define PP 256
#define CC 151
#define RR 51
#define CM 160                 // padded C (5 tiles of 32)
#define KS 64                  // split-K: 4 i's per block
#define NROW (NB*PP)           // 1024
#define RELTOT (NB*PP*PP*RR)   // 13,369,344 floats
#define ALIM (RELTOT - 8)
#define MLB 10240              // halves per l in m-layout: 8 oct * 160 c * 8 j

typedef _Float16 half8 __attribute__((ext_vector_type(8)));
typedef float floatx16 __attribute__((ext_vector_type(16)));

// ws layout (bytes): m1g, m2g, part
#define OFF_M1 ((size_t)0)
#define OFF_M2 (OFF_M1 + (size_t)CC*MLB*2)     // +3,092,480
#define OFF_PT (OFF_M2 + (size_t)CC*MLB*2)     // part: 64*1024*160*4 = 41.9 MB

// ---------------------------------------------------------------------------
// K1: streaming-friendly M layout.
// m1g[l][oct][c][j] = w_r * M[l][c][oct*8+j]   (r = oct*8+j)
// m2g[l][oct][c][j] = w_r * M[c][l][oct*8+j]
// w_0 = 0.5, w_{r>=1} = 0.25; zero for r >= 51 or c >= 151.
// ---------------------------------------------------------------------------
__global__ __launch_bounds__(256) void prep_kernel(const float* __restrict__ M,
                                                   _Float16* __restrict__ m1,
                                                   _Float16* __restrict__ m2,
                                                   float* __restrict__ out) {
    const int l = blockIdx.x;      // 0..150
    const int mat = blockIdx.y;    // 0,1
    if (l == 0 && mat == 0 && threadIdx.x == 0) *out = 0.f;
    _Float16* dst = (mat ? m2 : m1) + (size_t)l * MLB;
    for (int e = threadIdx.x; e < MLB; e += 256) {
        int oct = e / 1280;
        int rem = e - oct * 1280;
        int c = rem >> 3, j = rem & 7;
        int r = oct * 8 + j;
        float v = 0.f;
        if (r < RR && c < CC) {
            size_t src = ((size_t)(mat ? c * CC + l : l * CC + c)) * RR + r;
            v = (r == 0 ? 0.5f : 0.25f) * M[src];
        }
        dst[e] = (_Float16)v;
    }
}

// ---------------------------------------------------------------------------
// K2 (fused transpose+GEMM, 32x32x16 MFMA) — barrier-free register pipeline:
//   - NO LDS, NO __syncthreads. B-fragments are 16B-aligned contiguous slices
//     of m1/m2 (L2-resident, 6 MB total) loaded per-lane as half8; the 4x
//     wave redundancy is absorbed by L2 (~34 TB/s). A stays per-lane f32
//     register loads. The compiler inserts precise counted vmcnt for
//     register deps — no structural vmcnt(0) drain anywhere in the K-loop.
//   - Explicit depth-2 software pipeline with NAMED stage registers; the
//     h-loop is fully unrolled so all array indices are compile-time (no
//     scratch), labs[] indexing static.
// Grid 512 = 4 img x 2 rowblk x 64 ks; 8 independent waves/CU.
// ---------------------------------------------------------------------------
__global__ __launch_bounds__(256, 2) void gemm_kernel(const float* __restrict__ rel,
                                                      const _Float16* __restrict__ m1,
                                                      const _Float16* __restrict__ m2,
                                                      const int* __restrict__ labels,
                                                      float* __restrict__ part) {
    const int tid  = threadIdx.x;
    const int ks   = blockIdx.x & 63;
    const int rbk  = (blockIdx.x >> 6) & 1;
    const int n    = blockIdx.x >> 7;
    const int wave = tid >> 6, lane = tid & 63;
    const int m32  = lane & 31, kh = lane >> 5;
    const int i0   = ks * 4;
    const int rowimg = rbk * 128 + wave * 32 + m32;   // this lane's A row (q, in-image)

    int labs[4];
    #pragma unroll
    for (int j = 0; j < 4; ++j) labs[j] = labels[n * PP + i0 + j];

    floatx16 acc[5];
    #pragma unroll
    for (int ct = 0; ct < 5; ++ct)
        #pragma unroll
        for (int r2 = 0; r2 < 16; ++r2) acc[ct][r2] = 0.f;

    // step h = (i_loc<<3) | (mat<<2) | t ; t = k16-step within the 64 r-slots
    auto loadA = [&](int h, float* v) {
        const int il = h >> 3, mh = (h >> 2) & 1, t = h & 3;
        const int i = i0 + il;
        const int r0 = t * 16 + kh * 8;
        int idx = mh ? ((n * PP + rowimg) * PP + i) * RR + r0
                     : ((n * PP + i) * PP + rowimg) * RR + r0;
        idx = min(idx, ALIM);     // only reachable on the i==q==255 diagonal (zeroed)
        const float* p = rel + idx;
        #pragma unroll
        for (int j = 0; j < 8; ++j) v[j] = p[j];
    };
    auto loadB = [&](int h, half8* b) {
        const int il = h >> 3, mh = (h >> 2) & 1, t = h & 3;
        const _Float16* p = (mh ? m2 : m1) + (size_t)labs[il] * MLB + t * 2560
                          + (size_t)(kh * 160 + m32) * 8;
        #pragma unroll
        for (int ct = 0; ct < 5; ++ct) b[ct] = *(const half8*)(p + ct * 256);
    };
    auto computeStep = [&](int h, const float* av, const half8* bv) {
        const int il = h >> 3;
        const bool dz = (i0 + il) == rowimg;   // diagonal i == q -> zero A row
        half8 a;
        #pragma unroll
        for (int j = 0; j < 8; ++j) a[j] = (_Float16)(dz ? 0.f : av[j]);
        #pragma unroll
        for (int ct = 0; ct < 5; ++ct)
            acc[ct] = __builtin_amdgcn_mfma_f32_32x32x16_f16(a, bv[ct], acc[ct], 0, 0, 0);
    };

    // depth-2 pipeline, named stages (compile-time indices everywhere)
    float aA[8], aB[8];
    half8 bA[5], bB[5];
    loadA(0, aA); loadB(0, bA);
    loadA(1, aB); loadB(1, bB);

    #pragma unroll
    for (int h = 0; h < 32; h += 2) {
        computeStep(h, aA, bA);
        if (h + 2 < 32) { loadA(h + 2, aA); loadB(h + 2, bA); }
        computeStep(h + 1, aB, bB);
        if (h + 3 < 32) { loadA(h + 3, aB); loadB(h + 3, bB); }
    }

    // C/D 32x32 layout (m74/m101): col = m32, row = (reg&3) + 8*(reg>>2) + 4*kh
    float* pb = part + ((size_t)ks * NROW + n * PP + rbk * 128 + wave * 32) * CM;
    #pragma unroll
    for (int ct = 0; ct < 5; ++ct)
        #pragma unroll
        for (int reg = 0; reg < 16; ++reg) {
            int row = (reg & 3) + 8 * (reg >> 2) + 4 * kh;
            pb[(size_t)row * CM + ct * 32 + m32] = acc[ct][reg];
        }
}

// ---------------------------------------------------------------------------
// K3: theta[row][c] = sum_ks part; loss = lse(theta) - theta[lab]; mean.
// ---------------------------------------------------------------------------
__global__ __launch_bounds__(256) void reduce_loss_kernel(const float* __restrict__ part,
                                                          const int* __restrict__ labels,
                                                          float* __restrict__ out) {
    __shared__ float th[CM];
    const int row = blockIdx.x;
    const int t = threadIdx.x;
    if (t < CM) {
        float s = 0.f;
        #pragma unroll
        for (int ks = 0; ks < KS; ++ks)
            s += part[((size_t)ks * NROW + row) * CM + t];
        th[t] = s;
    }
    __syncthreads();
    if (t < 64) {
        float v0 = (t < CC)       ? th[t]       : -INFINITY;
        float v1 = (t + 64 < CC)  ? th[t + 64]  : -INFINITY;
        float v2 = (t + 128 < CC) ? th[t + 128] : -INFINITY;
        float m = fmaxf(v0, fmaxf(v1, v2));
        #pragma unroll
        for (int o = 32; o > 0; o >>= 1) m = fmaxf(m, __shfl_xor(m, o, 64));
        float s = 0.f;
        if (t < CC)       s += expf(v0 - m);
        if (t + 64 < CC)  s += expf(v1 - m);
        if (t + 128 < CC) s += expf(v2 - m);
        #pragma unroll
        for (int o = 32; o > 0; o >>= 1) s += __shfl_xor(s, o, 64);
        if (t == 0) {
            atomicAdd(out, (m + logf(s) - th[labels[row]]) * (1.0f / NROW));
        }
    }
}

// ---------------------------------------------------------------------------
extern "C" void kernel_launch(void* const* d_in, const int* in_sizes, int n_in,
                              void* d_out, int out_size, void* d_ws, size_t ws_size,
                              hipStream_t stream) {
    // inputs: 0=roi_scores (unused), 1=rel_scores, 2=relationship_mat,
    //         3=roi_labels, 4=num_images (fixed B=4)
    const float* rel    = (const float*)d_in[1];
    const float* relmat = (const float*)d_in[2];
    const int*   labels = (const int*)d_in[3];
    float* out = (float*)d_out;
    char* ws = (char*)d_ws;

    _Float16* m1 = (_Float16*)(ws + OFF_M1);
    _Float16* m2 = (_Float16*)(ws + OFF_M2);
    float*  part = (float*)(ws + OFF_PT);

    prep_kernel<<<dim3(CC, 2), 256, 0, stream>>>(relmat, m1, m2, out);
    gemm_kernel<<<NB * 2 * KS, 256, 0, stream>>>(rel, m1, m2, labels, part);
    reduce_loss_kernel<<<NROW, 256, 0, stream>>>(part, labels, out);
}

// Round 3
// 172.733 us; speedup vs baseline: 1.3458x; 1.0021x over previous
//
#include <hip/hip_runtime.h>
#include <math.h>

#define NB 4
#define PP 256
#define CC 151
#define RR 51
#define CM 160                 // padded C (5 tiles of 32)
#define KS 64                  // split-K: 4 i's per block
#define NROW (NB*PP)           // 1024
#define RELTOT (NB*PP*PP*RR)   // 13,369,344 floats
#define ALIM (RELTOT - 8)
#define MLB 10240              // halves per l in m-layout: 8 oct * 160 c * 8 j

typedef _Float16 half8 __attribute__((ext_vector_type(8)));
typedef float floatx16 __attribute__((ext_vector_type(16)));

// ws layout (bytes): m1g, m2g, part
#define OFF_M1 ((size_t)0)
#define OFF_M2 (OFF_M1 + (size_t)CC*MLB*2)     // +3,092,480
#define OFF_PT (OFF_M2 + (size_t)CC*MLB*2)     // part: 64*1024*160*4 = 41.9 MB

// ---------------------------------------------------------------------------
// K1: streaming-friendly M layout.
// m1g[l][oct][c][j] = w_r * M[l][c][oct*8+j]   (r = oct*8+j)
// m2g[l][oct][c][j] = w_r * M[c][l][oct*8+j]
// w_0 = 0.5, w_{r>=1} = 0.25; zero for r >= 51 or c >= 151.
// ---------------------------------------------------------------------------
__global__ __launch_bounds__(256) void prep_kernel(const float* __restrict__ M,
                                                   _Float16* __restrict__ m1,
                                                   _Float16* __restrict__ m2,
                                                   float* __restrict__ out) {
    const int l = blockIdx.x;      // 0..150
    const int mat = blockIdx.y;    // 0,1
    if (l == 0 && mat == 0 && threadIdx.x == 0) *out = 0.f;
    _Float16* dst = (mat ? m2 : m1) + (size_t)l * MLB;
    for (int e = threadIdx.x; e < MLB; e += 256) {
        int oct = e / 1280;
        int rem = e - oct * 1280;
        int c = rem >> 3, j = rem & 7;
        int r = oct * 8 + j;
        float v = 0.f;
        if (r < RR && c < CC) {
            size_t src = ((size_t)(mat ? c * CC + l : l * CC + c)) * RR + r;
            v = (r == 0 ? 0.5f : 0.25f) * M[src];
        }
        dst[e] = (_Float16)v;
    }
}

// ---------------------------------------------------------------------------
// K2 (fused transpose+GEMM, 32x32x16 MFMA) — barrier-free DEPTH-4 register
// pipeline:
//   - NO LDS, NO __syncthreads. B-fragments are 16B-aligned contiguous slices
//     of m1/m2 (L2-resident, 6 MB total) loaded per-lane as half8; A is
//     per-lane f32 register loads. Compiler inserts precise counted vmcnt
//     for register deps — no structural vmcnt(0) drain in the K-loop.
//   - Occupancy is grid-capped (2 blocks/CU = 2 waves/SIMD), so latency
//     hiding must come from ILP: 4 named pipeline stages (~28 VGPR each,
//     well under the 256/wave budget at this occupancy) give an issue->use
//     distance of 3 compute steps, covering ~900-cyc HBM latency with
//     2 waves/SIMD interleaved. Loop fully unrolled: all indices static.
// Grid 512 = 4 img x 2 rowblk x 64 ks.
// ---------------------------------------------------------------------------
__global__ __launch_bounds__(256, 2) void gemm_kernel(const float* __restrict__ rel,
                                                      const _Float16* __restrict__ m1,
                                                      const _Float16* __restrict__ m2,
                                                      const int* __restrict__ labels,
                                                      float* __restrict__ part) {
    const int tid  = threadIdx.x;
    const int ks   = blockIdx.x & 63;
    const int rbk  = (blockIdx.x >> 6) & 1;
    const int n    = blockIdx.x >> 7;
    const int wave = tid >> 6, lane = tid & 63;
    const int m32  = lane & 31, kh = lane >> 5;
    const int i0   = ks * 4;
    const int rowimg = rbk * 128 + wave * 32 + m32;   // this lane's A row (q, in-image)

    int labs[4];
    #pragma unroll
    for (int j = 0; j < 4; ++j) labs[j] = labels[n * PP + i0 + j];

    floatx16 acc[5];
    #pragma unroll
    for (int ct = 0; ct < 5; ++ct)
        #pragma unroll
        for (int r2 = 0; r2 < 16; ++r2) acc[ct][r2] = 0.f;

    // step h = (i_loc<<3) | (mat<<2) | t ; t = k16-step within the 64 r-slots
    auto loadA = [&](int h, float* v) {
        const int il = h >> 3, mh = (h >> 2) & 1, t = h & 3;
        const int i = i0 + il;
        const int r0 = t * 16 + kh * 8;
        int idx = mh ? ((n * PP + rowimg) * PP + i) * RR + r0
                     : ((n * PP + i) * PP + rowimg) * RR + r0;
        idx = min(idx, ALIM);     // only reachable on the i==q==255 diagonal (zeroed)
        const float* p = rel + idx;
        #pragma unroll
        for (int j = 0; j < 8; ++j) v[j] = p[j];
    };
    auto loadB = [&](int h, half8* b) {
        const int il = h >> 3, mh = (h >> 2) & 1, t = h & 3;
        const _Float16* p = (mh ? m2 : m1) + (size_t)labs[il] * MLB + t * 2560
                          + (size_t)(kh * 160 + m32) * 8;
        #pragma unroll
        for (int ct = 0; ct < 5; ++ct) b[ct] = *(const half8*)(p + ct * 256);
    };
    auto computeStep = [&](int h, const float* av, const half8* bv) {
        const int il = h >> 3;
        const bool dz = (i0 + il) == rowimg;   // diagonal i == q -> zero A row
        half8 a;
        #pragma unroll
        for (int j = 0; j < 8; ++j) a[j] = (_Float16)(dz ? 0.f : av[j]);
        #pragma unroll
        for (int ct = 0; ct < 5; ++ct)
            acc[ct] = __builtin_amdgcn_mfma_f32_32x32x16_f16(a, bv[ct], acc[ct], 0, 0, 0);
    };

    // depth-4 pipeline, named stages (compile-time indices everywhere)
    float aS0[8], aS1[8], aS2[8], aS3[8];
    half8 bS0[5], bS1[5], bS2[5], bS3[5];
    loadA(0, aS0); loadB(0, bS0);
    loadA(1, aS1); loadB(1, bS1);
    loadA(2, aS2); loadB(2, bS2);
    loadA(3, aS3); loadB(3, bS3);

    #pragma unroll
    for (int h = 0; h < 32; h += 4) {
        computeStep(h + 0, aS0, bS0);
        if (h + 4 < 32) { loadA(h + 4, aS0); loadB(h + 4, bS0); }
        computeStep(h + 1, aS1, bS1);
        if (h + 5 < 32) { loadA(h + 5, aS1); loadB(h + 5, bS1); }
        computeStep(h + 2, aS2, bS2);
        if (h + 6 < 32) { loadA(h + 6, aS2); loadB(h + 6, bS2); }
        computeStep(h + 3, aS3, bS3);
        if (h + 7 < 32) { loadA(h + 7, aS3); loadB(h + 7, bS3); }
    }

    // C/D 32x32 layout (m74/m101): col = m32, row = (reg&3) + 8*(reg>>2) + 4*kh
    float* pb = part + ((size_t)ks * NROW + n * PP + rbk * 128 + wave * 32) * CM;
    #pragma unroll
    for (int ct = 0; ct < 5; ++ct)
        #pragma unroll
        for (int reg = 0; reg < 16; ++reg) {
            int row = (reg & 3) + 8 * (reg >> 2) + 4 * kh;
            pb[(size_t)row * CM + ct * 32 + m32] = acc[ct][reg];
        }
}

// ---------------------------------------------------------------------------
// K3: theta[row][c] = sum_ks part; loss = lse(theta) - theta[lab]; mean.
// ---------------------------------------------------------------------------
__global__ __launch_bounds__(256) void reduce_loss_kernel(const float* __restrict__ part,
                                                          const int* __restrict__ labels,
                                                          float* __restrict__ out) {
    __shared__ float th[CM];
    const int row = blockIdx.x;
    const int t = threadIdx.x;
    if (t < CM) {
        float s = 0.f;
        #pragma unroll
        for (int ks = 0; ks < KS; ++ks)
            s += part[((size_t)ks * NROW + row) * CM + t];
        th[t] = s;
    }
    __syncthreads();
    if (t < 64) {
        float v0 = (t < CC)       ? th[t]       : -INFINITY;
        float v1 = (t + 64 < CC)  ? th[t + 64]  : -INFINITY;
        float v2 = (t + 128 < CC) ? th[t + 128] : -INFINITY;
        float m = fmaxf(v0, fmaxf(v1, v2));
        #pragma unroll
        for (int o = 32; o > 0; o >>= 1) m = fmaxf(m, __shfl_xor(m, o, 64));
        float s = 0.f;
        if (t < CC)       s += expf(v0 - m);
        if (t + 64 < CC)  s += expf(v1 - m);
        if (t + 128 < CC) s += expf(v2 - m);
        #pragma unroll
        for (int o = 32; o > 0; o >>= 1) s += __shfl_xor(s, o, 64);
        if (t == 0) {
            atomicAdd(out, (m + logf(s) - th[labels[row]]) * (1.0f / NROW));
        }
    }
}

// ---------------------------------------------------------------------------
extern "C" void kernel_launch(void* const* d_in, const int* in_sizes, int n_in,
                              void* d_out, int out_size, void* d_ws, size_t ws_size,
                              hipStream_t stream) {
    // inputs: 0=roi_scores (unused), 1=rel_scores, 2=relationship_mat,
    //         3=roi_labels, 4=num_images (fixed B=4)
    const float* rel    = (const float*)d_in[1];
    const float* relmat = (const float*)d_in[2];
    const int*   labels = (const int*)d_in[3];
    float* out = (float*)d_out;
    char* ws = (char*)d_ws;

    _Float16* m1 = (_Float16*)(ws + OFF_M1);
    _Float16* m2 = (_Float16*)(ws + OFF_M2);
    float*  part = (float*)(ws + OFF_PT);

    prep_kernel<<<dim3(CC, 2), 256, 0, stream>>>(relmat, m1, m2, out);
    gemm_kernel<<<NB * 2 * KS, 256, 0, stream>>>(rel, m1, m2, labels, part);
    reduce_loss_kernel<<<NROW, 256, 0, stream>>>(part, labels, out);
}